// Round 5
// baseline (259.040 us; speedup 1.0000x reference)
//
#include <hip/hip_runtime.h>
#include <stdint.h>

#define K_DIM 4096
#define N_DIM 4096
#define SIGMA 20.0f
#define EPSQ 1e-8f

typedef __attribute__((ext_vector_type(4))) int i32x4;

// global_load_lds width-16 helper (addrspace casts: generic->AS1 / ->AS3)
#define GLDS16(gp, lp)                                                         \
  __builtin_amdgcn_global_load_lds(                                            \
      (const __attribute__((address_space(1))) unsigned int*)(const void*)(gp),\
      (__attribute__((address_space(3))) unsigned int*)(void*)(lp), 16, 0, 0)

// ---------------------------------------------------------------------------
// Kernel 1: per-row absmax -> row_scale, outlier column mask, quantize x->int8
// Mask is 8-way REPLICATED (replica = m&7): 4096 blocks plain-storing to 8 hot
// words forced cross-XCD L2 line ping-pong (suspected chunk of the 158us
// non-gemm time). Replication cuts writers/line 8x and keeps them XCD-local.
// ---------------------------------------------------------------------------
__global__ __launch_bounds__(256) void k_rowquant(
    const float* __restrict__ x, float* __restrict__ row_scale,
    int* __restrict__ mask, int8_t* __restrict__ qx)
{
  const int m = blockIdx.x;
  const int t = threadIdx.x;
  int* mrep = mask + ((m & 7) << 12);   // replica base (4096 ints each)
  const float4* xr = (const float4*)(x + (size_t)m * K_DIM);
  float4 v[4];
  float amax = 0.0f;
#pragma unroll
  for (int i = 0; i < 4; ++i) {
    v[i] = xr[t + i * 256];
    float a0 = fabsf(v[i].x), a1 = fabsf(v[i].y);
    float a2 = fabsf(v[i].z), a3 = fabsf(v[i].w);
    amax = fmaxf(amax, fmaxf(fmaxf(a0, a1), fmaxf(a2, a3)));
    int kbase = (t + i * 256) * 4;
    if (a0 > SIGMA) mrep[kbase + 0] = 1;
    if (a1 > SIGMA) mrep[kbase + 1] = 1;
    if (a2 > SIGMA) mrep[kbase + 2] = 1;
    if (a3 > SIGMA) mrep[kbase + 3] = 1;
  }
#pragma unroll
  for (int off = 32; off > 0; off >>= 1)
    amax = fmaxf(amax, __shfl_down(amax, off, 64));
  __shared__ float smax[4];
  __shared__ float sscale;
  if ((t & 63) == 0) smax[t >> 6] = amax;
  __syncthreads();
  if (t == 0) {
    float ms = fmaxf(fmaxf(smax[0], smax[1]), fmaxf(smax[2], smax[3]));
    float rs = fmaxf(ms / 127.0f, EPSQ);  // IEEE divide: bit-match jnp
    sscale = rs;
    row_scale[m] = rs;
  }
  __syncthreads();
  const float rs = sscale;
  uint32_t* qxo = (uint32_t*)(qx + (size_t)m * K_DIM);
#pragma unroll
  for (int i = 0; i < 4; ++i) {
    int q0 = (int)rintf(fminf(fmaxf(v[i].x / rs, -128.0f), 127.0f));
    int q1 = (int)rintf(fminf(fmaxf(v[i].y / rs, -128.0f), 127.0f));
    int q2 = (int)rintf(fminf(fmaxf(v[i].z / rs, -128.0f), 127.0f));
    int q3 = (int)rintf(fminf(fmaxf(v[i].w / rs, -128.0f), 127.0f));
    uint32_t packed = (uint32_t)(q0 & 0xff) | ((uint32_t)(q1 & 0xff) << 8) |
                      ((uint32_t)(q2 & 0xff) << 16) | ((uint32_t)(q3 & 0xff) << 24);
    qxo[t + i * 256] = packed;
  }
}

// ---------------------------------------------------------------------------
// Kernel 2: collapse 8 mask replicas -> final mask (into replica 0) + compact
// outlier column list. 16 blocks x 256 threads; each k owned by one thread.
// ---------------------------------------------------------------------------
__global__ __launch_bounds__(256) void k_collapse(
    int* __restrict__ mask, int* __restrict__ outlist, int* __restrict__ count)
{
  int k = blockIdx.x * 256 + threadIdx.x;
  int v = 0;
#pragma unroll
  for (int r = 0; r < 8; ++r) v |= mask[(r << 12) + k];
  mask[k] = v;   // final mask lives in replica 0
  if (v) {
    int idx = atomicAdd(count, 1);
    outlist[idx] = k;
  }
}

// ---------------------------------------------------------------------------
// Kernel 3: weight quant: zero outlier cols, per-row absmax -> q_scale, int8
// ---------------------------------------------------------------------------
__global__ __launch_bounds__(256) void k_wquant(
    const float* __restrict__ w, const int* __restrict__ mask,
    float* __restrict__ q_scale, int8_t* __restrict__ qw)
{
  const int n = blockIdx.x;
  const int t = threadIdx.x;
  const float4* wr = (const float4*)(w + (size_t)n * K_DIM);
  const int4* mr = (const int4*)mask;
  float4 v[4];
  float amax = 0.0f;
#pragma unroll
  for (int i = 0; i < 4; ++i) {
    float4 vv = wr[t + i * 256];
    int4 mm = mr[t + i * 256];
    vv.x = mm.x ? 0.0f : vv.x;
    vv.y = mm.y ? 0.0f : vv.y;
    vv.z = mm.z ? 0.0f : vv.z;
    vv.w = mm.w ? 0.0f : vv.w;
    v[i] = vv;
    amax = fmaxf(amax, fmaxf(fmaxf(fabsf(vv.x), fabsf(vv.y)),
                             fmaxf(fabsf(vv.z), fabsf(vv.w))));
  }
#pragma unroll
  for (int off = 32; off > 0; off >>= 1)
    amax = fmaxf(amax, __shfl_down(amax, off, 64));
  __shared__ float smax[4];
  __shared__ float sscale;
  if ((t & 63) == 0) smax[t >> 6] = amax;
  __syncthreads();
  if (t == 0) {
    float ms = fmaxf(fmaxf(smax[0], smax[1]), fmaxf(smax[2], smax[3]));
    float qs = fmaxf(ms / 127.0f, EPSQ);
    sscale = qs;
    q_scale[n] = qs;
  }
  __syncthreads();
  const float qs = sscale;
  uint32_t* qwo = (uint32_t*)(qw + (size_t)n * K_DIM);
#pragma unroll
  for (int i = 0; i < 4; ++i) {
    int q0 = (int)rintf(fminf(fmaxf(v[i].x / qs, -128.0f), 127.0f));
    int q1 = (int)rintf(fminf(fmaxf(v[i].y / qs, -128.0f), 127.0f));
    int q2 = (int)rintf(fminf(fmaxf(v[i].z / qs, -128.0f), 127.0f));
    int q3 = (int)rintf(fminf(fmaxf(v[i].w / qs, -128.0f), 127.0f));
    uint32_t packed = (uint32_t)(q0 & 0xff) | ((uint32_t)(q1 & 0xff) << 8) |
                      ((uint32_t)(q2 & 0xff) << 16) | ((uint32_t)(q3 & 0xff) << 24);
    qwo[t + i * 256] = packed;
  }
}

// ---------------------------------------------------------------------------
// Kernel 4: int8 GEMM, 256x256 tile, BK=64, 8 waves (2Mx4N), 512 threads.
// Round-5: FAITHFUL m201 fine-phase schedule (the one ingredient not yet
// replicated; m196 isolated fine granularity as the lever, m218 showed
// counted-vmcnt pays only inside it). Per K-tile: 4 QUADRANT phases, each
//   { 6 ds_read_b128 (A-half 4 + B-half 2); 1 global_load_lds;
//     s_barrier; lgkmcnt(0); setprio(1); 8 MFMA; setprio(0); s_barrier }
// vmcnt(8) once per K-tile (before the last barrier): tiles kt+2,kt+3 stay in
// flight, kt+1 is landed. 4-buffer LDS ring (128 KB), stage tile kt+3 split
// 1 GLDS per phase. Rounds 1-4 (coarse 1-2 phase variants, reg prefetch) all
// 88-104us / 27-32% MfmaUtil; this is the granularity A/B.
// 64B LDS rows, 2-row-unit XOR chunk swizzle c_phys = c ^ ((row>>1)&3),
// applied on the GLOBAL source side for staging and on LDS read offsets.
// ---------------------------------------------------------------------------
__global__ __launch_bounds__(512, 2) void k_gemm(
    const int8_t* __restrict__ qx, const int8_t* __restrict__ qw,
    const float* __restrict__ row_scale, const float* __restrict__ q_scale,
    const float* __restrict__ bias,
    const float* __restrict__ x, const float* __restrict__ w,
    const int* __restrict__ outlist, const int* __restrict__ outcount,
    float* __restrict__ out)
{
  __shared__ int8_t As[4][256 * 64];   // 4 x 16 KB
  __shared__ int8_t Bs[4][256 * 64];   // 4 x 16 KB   -> 128 KB total

  const int t = threadIdx.x;            // 0..511
  const int m0 = blockIdx.y * 256;
  const int n0 = blockIdx.x * 256;
  const int lane = t & 63;
  const int wave = t >> 6;              // 0..7
  const int wm = (wave >> 2) * 128;     // 0 or 128
  const int wn = (wave & 3) * 64;       // 0,64,128,192
  const int lrow = lane & 15;
  const int kg = lane >> 4;             // 0..3

  i32x4 acc[8][4] = {};

  // staging: thread t covers row t>>2 (0..127 within half-tile), phys chunk t&3
  const int srow = t >> 2;
  const int sclog = (t & 3) ^ ((srow >> 1) & 3);
  const int8_t* gA = qx + (size_t)(m0 + srow) * K_DIM + sclog * 16;
  const int8_t* gB = qw + (size_t)(n0 + srow) * K_DIM + sclog * 16;

  // loop-invariant swizzled LDS read offsets (within one 16 KB tile buffer)
  int offA[8], offB[4];
#pragma unroll
  for (int i = 0; i < 8; ++i) {
    int rA = wm + i * 16 + lrow;
    offA[i] = rA * 64 + ((kg ^ ((rA >> 1) & 3)) * 16);
  }
#pragma unroll
  for (int j = 0; j < 4; ++j) {
    int rB = wn + j * 16 + lrow;
    offB[j] = rB * 64 + ((kg ^ ((rB >> 1) & 3)) * 16);
  }

  // one GLDS instruction each (stage split across the 4 phases)
#define ST_A_LO(b, tt) GLDS16(gA + (size_t)(tt) * 64, &As[b][t * 16])
#define ST_A_HI(b, tt) GLDS16(gA + (size_t)128 * K_DIM + (size_t)(tt) * 64, &As[b][8192 + t * 16])
#define ST_B_LO(b, tt) GLDS16(gB + (size_t)(tt) * 64, &Bs[b][t * 16])
#define ST_B_HI(b, tt) GLDS16(gB + (size_t)128 * K_DIM + (size_t)(tt) * 64, &Bs[b][8192 + t * 16])

  // quadrant phase: IH = A-half (0/1), JH = B-half (0/1); 6 ds_read + 8 MFMA
#define PHASE(aC, bC, IH, JH, STAGE_STMT) do {                                 \
    i32x4 fa0 = *(const i32x4*)((aC) + offA[(IH) * 4 + 0]);                    \
    i32x4 fa1 = *(const i32x4*)((aC) + offA[(IH) * 4 + 1]);                    \
    i32x4 fa2 = *(const i32x4*)((aC) + offA[(IH) * 4 + 2]);                    \
    i32x4 fa3 = *(const i32x4*)((aC) + offA[(IH) * 4 + 3]);                    \
    i32x4 fb0 = *(const i32x4*)((bC) + offB[(JH) * 2 + 0]);                    \
    i32x4 fb1 = *(const i32x4*)((bC) + offB[(JH) * 2 + 1]);                    \
    STAGE_STMT;                                                                \
    __builtin_amdgcn_s_barrier();                                              \
    asm volatile("s_waitcnt lgkmcnt(0)" ::: "memory");                         \
    __builtin_amdgcn_s_setprio(1);                                             \
    acc[(IH)*4+0][(JH)*2+0] = __builtin_amdgcn_mfma_i32_16x16x64_i8(fa0, fb0, acc[(IH)*4+0][(JH)*2+0], 0, 0, 0); \
    acc[(IH)*4+1][(JH)*2+0] = __builtin_amdgcn_mfma_i32_16x16x64_i8(fa1, fb0, acc[(IH)*4+1][(JH)*2+0], 0, 0, 0); \
    acc[(IH)*4+2][(JH)*2+0] = __builtin_amdgcn_mfma_i32_16x16x64_i8(fa2, fb0, acc[(IH)*4+2][(JH)*2+0], 0, 0, 0); \
    acc[(IH)*4+3][(JH)*2+0] = __builtin_amdgcn_mfma_i32_16x16x64_i8(fa3, fb0, acc[(IH)*4+3][(JH)*2+0], 0, 0, 0); \
    acc[(IH)*4+0][(JH)*2+1] = __builtin_amdgcn_mfma_i32_16x16x64_i8(fa0, fb1, acc[(IH)*4+0][(JH)*2+1], 0, 0, 0); \
    acc[(IH)*4+1][(JH)*2+1] = __builtin_amdgcn_mfma_i32_16x16x64_i8(fa1, fb1, acc[(IH)*4+1][(JH)*2+1], 0, 0, 0); \
    acc[(IH)*4+2][(JH)*2+1] = __builtin_amdgcn_mfma_i32_16x16x64_i8(fa2, fb1, acc[(IH)*4+2][(JH)*2+1], 0, 0, 0); \
    acc[(IH)*4+3][(JH)*2+1] = __builtin_amdgcn_mfma_i32_16x16x64_i8(fa3, fb1, acc[(IH)*4+3][(JH)*2+1], 0, 0, 0); \
    __builtin_amdgcn_s_setprio(0);                                             \
  } while (0)

  // prologue: fill 3 tiles (12 GLDS/wave); vmcnt(8) -> tile 0 landed
  ST_A_LO(0, 0); ST_A_HI(0, 0); ST_B_LO(0, 0); ST_B_HI(0, 0);
  ST_A_LO(1, 1); ST_A_HI(1, 1); ST_B_LO(1, 1); ST_B_HI(1, 1);
  ST_A_LO(2, 2); ST_A_HI(2, 2); ST_B_LO(2, 2); ST_B_HI(2, 2);
  asm volatile("s_waitcnt vmcnt(8)" ::: "memory");
  __builtin_amdgcn_s_barrier();

#pragma unroll 4
  for (int kt = 0; kt < 64; ++kt) {
    const int cur = kt & 3;
    const int nx = (kt + 3) & 3;        // buffer being (re)staged
    const int ktn = (kt + 3) & 63;      // wrap staging keeps vmcnt uniform
    const int8_t* a = &As[cur][0];
    const int8_t* b = &Bs[cur][0];

    PHASE(a, b, 0, 0, ST_A_LO(nx, ktn));
    __builtin_amdgcn_s_barrier();
    PHASE(a, b, 0, 1, ST_A_HI(nx, ktn));
    __builtin_amdgcn_s_barrier();
    PHASE(a, b, 1, 0, ST_B_LO(nx, ktn));
    __builtin_amdgcn_s_barrier();
    PHASE(a, b, 1, 1, ST_B_HI(nx, ktn));
    // per-K-tile drain: all this tile's ds_reads already lgkm-drained by their
    // phases (WAR ok); vmcnt(8) -> tile kt+1 landed (kt+2,kt+3 in flight)
    asm volatile("s_waitcnt vmcnt(8)" ::: "memory");
    __builtin_amdgcn_s_barrier();
  }

#undef PHASE
#undef ST_A_LO
#undef ST_A_HI
#undef ST_B_LO
#undef ST_B_HI

  // ---- epilogue: stage outlier x / w slices into LDS (reuse buffer 0) ----
  __syncthreads();  // full drain (vmcnt 0 + lgkm 0 + barrier): wrap gloads land
  float* xsh = (float*)&As[0][0];   // [256][8]
  float* wsh = (float*)&Bs[0][0];   // [256][8]
  const int cnt = *outcount;
  const int cs = cnt < 8 ? cnt : 8;
#pragma unroll
  for (int u = 0; u < 4; ++u) {
    int idx = t * 4 + u;   // 0..2047
    int rr = idx >> 3;     // 0..255
    int oo = idx & 7;
    float xv = 0.0f, wv = 0.0f;
    if (oo < cs) {
      int kcol = outlist[oo];
      xv = x[(size_t)(m0 + rr) * K_DIM + kcol];
      wv = w[(size_t)(n0 + rr) * K_DIM + kcol];
    }
    xsh[rr * 8 + oo] = xv;
    wsh[rr * 8 + oo] = wv;
  }
  __syncthreads();

  float qs[4], bv[4];
  int gn[4];
#pragma unroll
  for (int j = 0; j < 4; ++j) {
    gn[j] = n0 + wn + j * 16 + lrow;
    qs[j] = q_scale[gn[j]];
    bv[j] = bias[gn[j]];
  }

  // C/D layout: col = lane&15, row = (lane>>4)*4 + reg  [m89/m101, dtype-indep]
#pragma unroll
  for (int i = 0; i < 8; ++i) {
#pragma unroll
    for (int r = 0; r < 4; ++r) {
      int ml = wm + i * 16 + kg * 4 + r;
      int gm = m0 + ml;
      float rs = row_scale[gm];
      float xvv[8];
#pragma unroll
      for (int o = 0; o < 8; ++o) xvv[o] = xsh[ml * 8 + o];
#pragma unroll
      for (int j = 0; j < 4; ++j) {
        int nl = wn + j * 16 + lrow;
        float corr = 0.0f;
#pragma unroll
        for (int o = 0; o < 8; ++o) corr += xvv[o] * wsh[nl * 8 + o];
        for (int o = 8; o < cnt; ++o)   // generality fallback (cold in practice)
          corr += x[(size_t)gm * K_DIM + outlist[o]] *
                  w[(size_t)gn[j] * K_DIM + outlist[o]];
        float val = (float)acc[i][j][r] * rs * qs[j] + corr + bv[j];
        out[(size_t)gm * N_DIM + gn[j]] = val;
      }
    }
  }
}

// ---------------------------------------------------------------------------
extern "C" void kernel_launch(void* const* d_in, const int* in_sizes, int n_in,
                              void* d_out, int out_size, void* d_ws, size_t ws_size,
                              hipStream_t stream) {
  const float* x = (const float*)d_in[0];      // [M,K] fp32 (M = B*S)
  const float* w = (const float*)d_in[1];      // [N,K] fp32
  const float* bias = (const float*)d_in[2];   // [N]
  float* out = (float*)d_out;                  // [M,N] fp32
  const int M = in_sizes[0] / K_DIM;           // 4096

  // workspace layout
  char* ws = (char*)d_ws;
  int* mask = (int*)(ws);                          // 8 replicas x 16 KB = 128 KB
  int* count = (int*)(ws + 131072);                // 4 B
  int* outlist = (int*)(ws + 135168);              // 16 KB
  float* row_scale = (float*)(ws + 151552);        // 16 KB
  float* q_scale = (float*)(ws + 167936);          // 16 KB
  int8_t* qx = (int8_t*)(ws + 262144);             // M*K int8 = 16 MB
  int8_t* qw = (int8_t*)(ws + 262144 + (size_t)M * K_DIM);  // N*K int8 = 16 MB

  hipMemsetAsync(ws, 0, 135680, stream);  // mask replicas + count
  k_rowquant<<<M, 256, 0, stream>>>(x, row_scale, mask, qx);
  k_collapse<<<K_DIM / 256, 256, 0, stream>>>(mask, outlist, count);
  k_wquant<<<N_DIM, 256, 0, stream>>>(w, mask, q_scale, qw);
  dim3 grid(N_DIM / 256, M / 256);
  k_gemm<<<grid, dim3(512, 1, 1), 0, stream>>>(qx, qw, row_scale, q_scale, bias,
                                               x, w, outlist, count, out);
}

// Round 6
// 258.944 us; speedup vs baseline: 1.0004x; 1.0004x over previous
//
#include <hip/hip_runtime.h>
#include <stdint.h>

#define K_DIM 4096
#define N_DIM 4096
#define SIGMA 20.0f
#define EPSQ 1e-8f

typedef __attribute__((ext_vector_type(4))) int i32x4;

// global_load_lds width-16 helper (addrspace casts: generic->AS1 / ->AS3)
#define GLDS16(gp, lp)                                                         \
  __builtin_amdgcn_global_load_lds(                                            \
      (const __attribute__((address_space(1))) unsigned int*)(const void*)(gp),\
      (__attribute__((address_space(3))) unsigned int*)(void*)(lp), 16, 0, 0)

// ---------------------------------------------------------------------------
// Kernel 1: per-row absmax -> row_scale, outlier column mask, quantize x->int8
// mask write is a PLAIN store (benign race: all writers store 1).
// ---------------------------------------------------------------------------
__global__ __launch_bounds__(256) void k_rowquant(
    const float* __restrict__ x, float* __restrict__ row_scale,
    int* __restrict__ mask, int8_t* __restrict__ qx)
{
  const int m = blockIdx.x;
  const int t = threadIdx.x;
  const float4* xr = (const float4*)(x + (size_t)m * K_DIM);
  float4 v[4];
  float amax = 0.0f;
#pragma unroll
  for (int i = 0; i < 4; ++i) {
    v[i] = xr[t + i * 256];
    float a0 = fabsf(v[i].x), a1 = fabsf(v[i].y);
    float a2 = fabsf(v[i].z), a3 = fabsf(v[i].w);
    amax = fmaxf(amax, fmaxf(fmaxf(a0, a1), fmaxf(a2, a3)));
    int kbase = (t + i * 256) * 4;
    if (a0 > SIGMA) mask[kbase + 0] = 1;
    if (a1 > SIGMA) mask[kbase + 1] = 1;
    if (a2 > SIGMA) mask[kbase + 2] = 1;
    if (a3 > SIGMA) mask[kbase + 3] = 1;
  }
#pragma unroll
  for (int off = 32; off > 0; off >>= 1)
    amax = fmaxf(amax, __shfl_down(amax, off, 64));
  __shared__ float smax[4];
  __shared__ float sscale;
  if ((t & 63) == 0) smax[t >> 6] = amax;
  __syncthreads();
  if (t == 0) {
    float ms = fmaxf(fmaxf(smax[0], smax[1]), fmaxf(smax[2], smax[3]));
    float rs = fmaxf(ms / 127.0f, EPSQ);  // IEEE divide: bit-match jnp
    sscale = rs;
    row_scale[m] = rs;
  }
  __syncthreads();
  const float rs = sscale;
  uint32_t* qxo = (uint32_t*)(qx + (size_t)m * K_DIM);
#pragma unroll
  for (int i = 0; i < 4; ++i) {
    int q0 = (int)rintf(fminf(fmaxf(v[i].x / rs, -128.0f), 127.0f));
    int q1 = (int)rintf(fminf(fmaxf(v[i].y / rs, -128.0f), 127.0f));
    int q2 = (int)rintf(fminf(fmaxf(v[i].z / rs, -128.0f), 127.0f));
    int q3 = (int)rintf(fminf(fmaxf(v[i].w / rs, -128.0f), 127.0f));
    uint32_t packed = (uint32_t)(q0 & 0xff) | ((uint32_t)(q1 & 0xff) << 8) |
                      ((uint32_t)(q2 & 0xff) << 16) | ((uint32_t)(q3 & 0xff) << 24);
    qxo[t + i * 256] = packed;
  }
}

// ---------------------------------------------------------------------------
// Kernel 2: weight quant (zero outlier cols, per-row absmax -> q_scale, int8)
// + fused mask compaction (block 0 only; mask complete via stream order).
// ---------------------------------------------------------------------------
__global__ __launch_bounds__(256) void k_wquant(
    const float* __restrict__ w, const int* __restrict__ mask,
    float* __restrict__ q_scale, int8_t* __restrict__ qw,
    int* __restrict__ outlist, int* __restrict__ count)
{
  const int n = blockIdx.x;
  const int t = threadIdx.x;
  if (n == 0) {
    for (int kk = t; kk < K_DIM; kk += 256) {
      if (mask[kk]) {
        int idx = atomicAdd(count, 1);
        outlist[idx] = kk;
      }
    }
  }
  const float4* wr = (const float4*)(w + (size_t)n * K_DIM);
  const int4* mr = (const int4*)mask;
  float4 v[4];
  float amax = 0.0f;
#pragma unroll
  for (int i = 0; i < 4; ++i) {
    float4 vv = wr[t + i * 256];
    int4 mm = mr[t + i * 256];
    vv.x = mm.x ? 0.0f : vv.x;
    vv.y = mm.y ? 0.0f : vv.y;
    vv.z = mm.z ? 0.0f : vv.z;
    vv.w = mm.w ? 0.0f : vv.w;
    v[i] = vv;
    amax = fmaxf(amax, fmaxf(fmaxf(fabsf(vv.x), fabsf(vv.y)),
                             fmaxf(fabsf(vv.z), fabsf(vv.w))));
  }
#pragma unroll
  for (int off = 32; off > 0; off >>= 1)
    amax = fmaxf(amax, __shfl_down(amax, off, 64));
  __shared__ float smax[4];
  __shared__ float sscale;
  if ((t & 63) == 0) smax[t >> 6] = amax;
  __syncthreads();
  if (t == 0) {
    float ms = fmaxf(fmaxf(smax[0], smax[1]), fmaxf(smax[2], smax[3]));
    float qs = fmaxf(ms / 127.0f, EPSQ);
    sscale = qs;
    q_scale[n] = qs;
  }
  __syncthreads();
  const float qs = sscale;
  uint32_t* qwo = (uint32_t*)(qw + (size_t)n * K_DIM);
#pragma unroll
  for (int i = 0; i < 4; ++i) {
    int q0 = (int)rintf(fminf(fmaxf(v[i].x / qs, -128.0f), 127.0f));
    int q1 = (int)rintf(fminf(fmaxf(v[i].y / qs, -128.0f), 127.0f));
    int q2 = (int)rintf(fminf(fmaxf(v[i].z / qs, -128.0f), 127.0f));
    int q3 = (int)rintf(fminf(fmaxf(v[i].w / qs, -128.0f), 127.0f));
    uint32_t packed = (uint32_t)(q0 & 0xff) | ((uint32_t)(q1 & 0xff) << 8) |
                      ((uint32_t)(q2 & 0xff) << 16) | ((uint32_t)(q3 & 0xff) << 24);
    qwo[t + i * 256] = packed;
  }
}

// ---------------------------------------------------------------------------
// Kernel 3: int8 GEMM. Round-6 change: 2 BLOCKS/CU (inter-block antiphase).
// R1-R5 proved schedule-invariance at 88-104us: with 1 block/CU, the block's
// barriers lockstep both waves of each SIMD, so the CU-wide LDS burst
// (~1500cy) and MFMA burst (~1300cy) serialize every K-tile (sum matches the
// measured 3337cy). m114/m97: independent blocks on one CU overlap naturally.
// Tile 128x256, grid 32x16 = 512 blocks = 2/CU. Ring-3 LDS (72 KB/block,
// 2x72=144 <= 160 KB). Schedule per K-tile = R3's proven minimal set:
// stage tile kt+2 (3 GLDS), read frags, MFMA cluster (setprio), then
// lgkm(0) [WAR] + vmcnt(3) [RAW: tile kt+1 landed, kt+2 in flight] +
// s_barrier + sched_barrier(0). 8 waves (2Mx4N), wave tile 64x64, acc 4x4
// -> VGPR fits 4 waves/SIMD (launch_bounds(512,4)).
// 64B LDS rows, 2-row-unit XOR chunk swizzle c_phys = c ^ ((row>>1)&3),
// applied on the GLOBAL source side for staging and on LDS read offsets
// (row+128 keeps the same swizzle since 128 ≡ 0 mod 4 after >>1).
// ---------------------------------------------------------------------------
__global__ __launch_bounds__(512, 4) void k_gemm(
    const int8_t* __restrict__ qx, const int8_t* __restrict__ qw,
    const float* __restrict__ row_scale, const float* __restrict__ q_scale,
    const float* __restrict__ bias,
    const float* __restrict__ x, const float* __restrict__ w,
    const int* __restrict__ outlist, const int* __restrict__ outcount,
    float* __restrict__ out)
{
  __shared__ int8_t As[3][128 * 64];   // 3 x 8 KB
  __shared__ int8_t Bs[3][256 * 64];   // 3 x 16 KB   -> 72 KB total

  const int t = threadIdx.x;            // 0..511
  const int m0 = blockIdx.y * 128;
  const int n0 = blockIdx.x * 256;
  const int lane = t & 63;
  const int wave = t >> 6;              // 0..7
  const int wm = (wave >> 2) * 64;      // 0 or 64
  const int wn = (wave & 3) * 64;       // 0,64,128,192
  const int lrow = lane & 15;
  const int kg = lane >> 4;             // 0..3

  i32x4 acc[4][4] = {};

  // staging: thread t covers row t>>2 (0..127), phys chunk t&3
  const int srow = t >> 2;
  const int sclog = (t & 3) ^ ((srow >> 1) & 3);
  const int8_t* gA = qx + (size_t)(m0 + srow) * K_DIM + sclog * 16;
  const int8_t* gB = qw + (size_t)(n0 + srow) * K_DIM + sclog * 16;

  // loop-invariant swizzled LDS read offsets
  int offA[4], offB[4];
#pragma unroll
  for (int i = 0; i < 4; ++i) {
    int rA = wm + i * 16 + lrow;
    offA[i] = rA * 64 + ((kg ^ ((rA >> 1) & 3)) * 16);
    int rB = wn + i * 16 + lrow;
    offB[i] = rB * 64 + ((kg ^ ((rB >> 1) & 3)) * 16);
  }

  // stage one K-tile (tt) into ring slot b: A = 1 GLDS, B = 2 GLDS per thread
#define STAGE(b, tt) do {                                                      \
    GLDS16(gA + (size_t)(tt) * 64, &As[b][t * 16]);                            \
    GLDS16(gB + (size_t)(tt) * 64, &Bs[b][t * 16]);                            \
    GLDS16(gB + (size_t)128 * K_DIM + (size_t)(tt) * 64, &Bs[b][8192 + t * 16]);\
  } while (0)

  // prologue: stage tiles 0,1 (6 GLDS); vmcnt(3) -> tile 0 landed
  STAGE(0, 0);
  STAGE(1, 1);
  asm volatile("s_waitcnt vmcnt(3)" ::: "memory");
  __builtin_amdgcn_s_barrier();
  __builtin_amdgcn_sched_barrier(0);

  // one K-tile: compute buf CUR, stage tile KT+2 into buf NXS
#define KTILE(KT, CUR, NXS) do {                                               \
    const int8_t* a = &As[CUR][0];                                             \
    const int8_t* b = &Bs[CUR][0];                                             \
    STAGE(NXS, ((KT) + 2) & 63);   /* wrap staging keeps vmcnt uniform */      \
    i32x4 af[4], bf[4];                                                        \
    _Pragma("unroll")                                                          \
    for (int i = 0; i < 4; ++i) af[i] = *(const i32x4*)(a + offA[i]);          \
    _Pragma("unroll")                                                          \
    for (int j = 0; j < 4; ++j) bf[j] = *(const i32x4*)(b + offB[j]);          \
    __builtin_amdgcn_s_setprio(1);                                             \
    _Pragma("unroll")                                                          \
    for (int i = 0; i < 4; ++i)                                                \
      _Pragma("unroll")                                                        \
      for (int j = 0; j < 4; ++j)                                              \
        acc[i][j] = __builtin_amdgcn_mfma_i32_16x16x64_i8(af[i], bf[j], acc[i][j], 0, 0, 0); \
    __builtin_amdgcn_s_setprio(0);                                             \
    asm volatile("s_waitcnt lgkmcnt(0)" ::: "memory");                         \
    asm volatile("s_waitcnt vmcnt(3)" ::: "memory");                           \
    __builtin_amdgcn_s_barrier();                                              \
    __builtin_amdgcn_sched_barrier(0);                                         \
  } while (0)

  for (int kt = 0; kt < 63; kt += 3) {
    KTILE(kt,     0, 2);
    KTILE(kt + 1, 1, 0);
    KTILE(kt + 2, 2, 1);
  }
  KTILE(63, 0, 2);   // 63 %3 == 0; stages wrap tile, never consumed

#undef KTILE
#undef STAGE

  // ---- epilogue: stage outlier x / w slices into LDS (reuse slot 0) ----
  __syncthreads();  // full drain (vmcnt 0 + lgkm 0 + barrier): wrap gloads land
  float* xsh = (float*)&As[0][0];   // [128][8] = 4 KB (fits 8 KB slot)
  float* wsh = (float*)&Bs[0][0];   // [256][8] = 8 KB (fits 16 KB slot)
  const int cnt = *outcount;
  const int cs = cnt < 8 ? cnt : 8;
#pragma unroll
  for (int u = 0; u < 2; ++u) {     // x slice: 128 rows x 8
    int idx = t * 2 + u;            // 0..1023
    int rr = idx >> 3;              // 0..127
    int oo = idx & 7;
    float xv = 0.0f;
    if (oo < cs) xv = x[(size_t)(m0 + rr) * K_DIM + outlist[oo]];
    xsh[rr * 8 + oo] = xv;
  }
#pragma unroll
  for (int u = 0; u < 4; ++u) {     // w slice: 256 rows x 8
    int idx = t * 4 + u;            // 0..2047
    int rr = idx >> 3;              // 0..255
    int oo = idx & 7;
    float wv = 0.0f;
    if (oo < cs) wv = w[(size_t)(n0 + rr) * K_DIM + outlist[oo]];
    wsh[rr * 8 + oo] = wv;
  }
  __syncthreads();

  float qs[4], bv[4];
  int gn[4];
#pragma unroll
  for (int j = 0; j < 4; ++j) {
    gn[j] = n0 + wn + j * 16 + lrow;
    qs[j] = q_scale[gn[j]];
    bv[j] = bias[gn[j]];
  }

  // C/D layout: col = lane&15, row = (lane>>4)*4 + reg  [m89/m101, dtype-indep]
#pragma unroll
  for (int i = 0; i < 4; ++i) {
#pragma unroll
    for (int r = 0; r < 4; ++r) {
      int ml = wm + i * 16 + kg * 4 + r;
      int gm = m0 + ml;
      float rs = row_scale[gm];
      float xvv[8];
#pragma unroll
      for (int o = 0; o < 8; ++o) xvv[o] = xsh[ml * 8 + o];
#pragma unroll
      for (int j = 0; j < 4; ++j) {
        int nl = wn + j * 16 + lrow;
        float corr = 0.0f;
#pragma unroll
        for (int o = 0; o < 8; ++o) corr += xvv[o] * wsh[nl * 8 + o];
        for (int o = 8; o < cnt; ++o)   // generality fallback (cold in practice)
          corr += x[(size_t)gm * K_DIM + outlist[o]] *
                  w[(size_t)gn[j] * K_DIM + outlist[o]];
        float val = (float)acc[i][j][r] * rs * qs[j] + corr + bv[j];
        out[(size_t)gm * N_DIM + gn[j]] = val;
      }
    }
  }
}

// ---------------------------------------------------------------------------
extern "C" void kernel_launch(void* const* d_in, const int* in_sizes, int n_in,
                              void* d_out, int out_size, void* d_ws, size_t ws_size,
                              hipStream_t stream) {
  const float* x = (const float*)d_in[0];      // [M,K] fp32 (M = B*S)
  const float* w = (const float*)d_in[1];      // [N,K] fp32
  const float* bias = (const float*)d_in[2];   // [N]
  float* out = (float*)d_out;                  // [M,N] fp32
  const int M = in_sizes[0] / K_DIM;           // 4096

  // workspace layout
  char* ws = (char*)d_ws;
  int* mask = (int*)(ws);                          // 16 KB
  int* count = (int*)(ws + 16384);                 // 4 B (memset region)
  int* outlist = (int*)(ws + 20480);               // 16 KB
  float* row_scale = (float*)(ws + 36864);         // 16 KB
  float* q_scale = (float*)(ws + 53248);           // 16 KB
  int8_t* qx = (int8_t*)(ws + 131072);             // M*K int8 = 16 MB
  int8_t* qw = (int8_t*)(ws + 131072 + (size_t)M * K_DIM);  // N*K int8 = 16 MB

  hipMemsetAsync(ws, 0, 20480, stream);  // mask + count
  k_rowquant<<<M, 256, 0, stream>>>(x, row_scale, mask, qx);
  k_wquant<<<N_DIM, 256, 0, stream>>>(w, mask, q_scale, qw, outlist, count);
  dim3 grid(N_DIM / 256, M / 128);
  k_gemm<<<grid, dim3(512, 1, 1), 0, stream>>>(qx, qw, row_scale, q_scale, bias,
                                               x, w, outlist, count, out);
}